// Round 5
// baseline (262.746 us; speedup 1.0000x reference)
//
#include <hip/hip_runtime.h>
#include <math.h>

typedef float f32x4 __attribute__((ext_vector_type(4)));
typedef short bf16x8 __attribute__((ext_vector_type(8)));
typedef _Float16 f16x8 __attribute__((ext_vector_type(8)));
typedef _Float16 f16x4 __attribute__((ext_vector_type(4)));

#define D 64
#define TT 8
#define RR 8

#define SCAN_TPB 256
#define SCAN_CH 4
#define SCAN_ELEMS (SCAN_TPB * SCAN_CH)   // 1024 elements per block

// deg_kernel: ONLY per-edge random returning atomics (no hot shared counters)
// -> can go wide for latency hiding (r2 lesson: wide grids are fine only when
//    the kernel has no per-block hot-counter atomics).
#define DEG_CH 2
#define SCAT_CH 4                          // r0-proven scatter shape (782 blocks)
#define SCORE_XB 256                       // score x-blocks (x4 waves = 1024 wave slots)
#define V2_XB 64                           // v2 x-blocks (x4 waves = 256 wave slots)
#define AGG_XB 256                         // agg_out x-blocks per type

// ---------------- scalar helpers ----------------
__device__ __forceinline__ float bf2f(unsigned short u) {
    union { unsigned int i; float f; } x;
    x.i = ((unsigned int)u) << 16;
    return x.f;
}
__device__ __forceinline__ unsigned short f2bf(float f) {
    union { float f; unsigned int i; } x;
    x.f = f;
    unsigned int i = x.i;
    unsigned int r = (i + 0x7FFFu + ((i >> 16) & 1u)) >> 16;   // RNE
    return (unsigned short)r;
}
struct BfPair { short hi; short lo; };
__device__ __forceinline__ BfPair split2(float x) {
    BfPair p;
    unsigned short h = f2bf(x);
    p.hi = (short)h;
    p.lo = (short)f2bf(x - bf2f(h));
    return p;
}
__device__ __forceinline__ void load_A_split(const float* __restrict__ p, bf16x8& ah, bf16x8& al) {
#pragma unroll
    for (int i = 0; i < 8; ++i) {
        BfPair s = split2(p[i]);
        ah[i] = s.hi; al[i] = s.lo;
    }
}
// bf16 split B fragment, canonical cols (agg_out: col = c*16+n)
__device__ __forceinline__ void load_B_split(const float* __restrict__ W, int ks, int c, int lane,
                                             bf16x8& bh, bf16x8& bl) {
    int n = lane & 15, q = lane >> 4;
#pragma unroll
    for (int i = 0; i < 8; ++i) {
        BfPair s = split2(W[(ks * 32 + q * 8 + i) * 64 + c * 16 + n]);
        bh[i] = s.hi; bl[i] = s.lo;
    }
}
// bf16 split B fragment, PERMUTED cols (proj: col = n*4+c -> lane n holds out cols 4n..4n+3;
// store address carries the permutation so kh16/qn/vn memory layout stays natural)
__device__ __forceinline__ void load_B_splitp(const float* __restrict__ W, int ks, int c, int lane,
                                              bf16x8& bh, bf16x8& bl) {
    int n = lane & 15, q = lane >> 4;
#pragma unroll
    for (int i = 0; i < 8; ++i) {
        BfPair s = split2(W[(ks * 32 + q * 8 + i) * 64 + n * 4 + c]);
        bh[i] = s.hi; bl[i] = s.lo;
    }
}
// fp16 split B fragment, PERMUTED cols (score: lane n's acc holds cols 4n..4n+3 ->
// q-dot loads one f16x4 per reg; legal since the dot reduces over all 64 cols)
__device__ __forceinline__ void load_B_split_f16(const float* __restrict__ W, int ks, int c, int lane,
                                                 f16x8& bh, f16x8& bl) {
    int n = lane & 15, q = lane >> 4;
#pragma unroll
    for (int i = 0; i < 8; ++i) {
        float w = W[(ks * 32 + q * 8 + i) * 64 + n * 4 + c];
        _Float16 h = (_Float16)w;
        bh[i] = h;
        bl[i] = (_Float16)(w - (float)h);
    }
}
// fp16 single B fragment, PERMUTED cols (V2 build: vector f16x4 stores)
__device__ __forceinline__ f16x8 load_B_frag_f16(const float* __restrict__ W, int ks, int c, int lane) {
    int n = lane & 15, q = lane >> 4;
    f16x8 r;
#pragma unroll
    for (int i = 0; i < 8; ++i)
        r[i] = (_Float16)W[(ks * 32 + q * 8 + i) * 64 + n * 4 + c];
    return r;
}

#define MFMA16(a, b, c) __builtin_amdgcn_mfma_f32_16x16x32_bf16(a, b, c, 0, 0, 0)
#define MFMAH(a, b, c)  __builtin_amdgcn_mfma_f32_16x16x32_f16(a, b, c, 0, 0, 0)

// 24 bf16 MFMAs: acc += (Ah+Al)@(Bh+Bl) dropping lo*lo
#define SPLIT_MFMA_BODY(acc, A0h, A0l, A1h, A1l, Bh, Bl)          \
    _Pragma("unroll")                                             \
    for (int c = 0; c < 4; ++c) {                                 \
        acc[c] = MFMA16(A0h, Bh[0][c], acc[c]);                   \
        acc[c] = MFMA16(A0l, Bh[0][c], acc[c]);                   \
        acc[c] = MFMA16(A0h, Bl[0][c], acc[c]);                   \
        acc[c] = MFMA16(A1h, Bh[1][c], acc[c]);                   \
        acc[c] = MFMA16(A1l, Bh[1][c], acc[c]);                   \
        acc[c] = MFMA16(A1h, Bl[1][c], acc[c]);                   \
    }

// ---------------- CSR build ----------------
// deg_kernel: per-edge deg histogram + erank, nothing else. Wide grid, no hot counters.
__global__ void deg_kernel(const int* __restrict__ dst,
                           int* __restrict__ deg, int* __restrict__ erank, int E) {
    const int stride = gridDim.x * blockDim.x;
    const int tid = blockIdx.x * blockDim.x + threadIdx.x;
#pragma unroll
    for (int i = 0; i < DEG_CH; ++i) {
        int e = tid + i * stride;
        if (e < E) erank[e] = atomicAdd(&deg[dst[e]], 1);
    }
}

// typehist_kernel: 8-bin et/nt histograms via LDS; few blocks -> few hot-counter atomics.
__global__ void typehist_kernel(const int* __restrict__ et, const int* __restrict__ nt,
                                int* __restrict__ rcnt, int* __restrict__ tcnt, int N, int E) {
    __shared__ int l_r[RR], l_t[TT];
    if (threadIdx.x < RR) l_r[threadIdx.x] = 0;
    if (threadIdx.x < TT) l_t[threadIdx.x] = 0;
    __syncthreads();
    const int stride = gridDim.x * blockDim.x;
    for (int e = blockIdx.x * blockDim.x + threadIdx.x; e < E; e += stride)
        atomicAdd(&l_r[et[e]], 1);
    for (int n = blockIdx.x * blockDim.x + threadIdx.x; n < N; n += stride)
        atomicAdd(&l_t[nt[n]], 1);
    __syncthreads();
    if (threadIdx.x < RR && l_r[threadIdx.x]) atomicAdd(&rcnt[threadIdx.x], l_r[threadIdx.x]);
    if (threadIdx.x < TT && l_t[threadIdx.x]) atomicAdd(&tcnt[threadIdx.x], l_t[threadIdx.x]);
}

// ---- 2-phase device-wide exclusive scan of deg[0..N) ----
__global__ void scan_sum_kernel(const int* __restrict__ deg, int* __restrict__ bsum, int N) {
    __shared__ int ws[SCAN_TPB / 64];
    int tid = threadIdx.x;
    int base = blockIdx.x * SCAN_ELEMS + tid * SCAN_CH;
    int s = 0;
#pragma unroll
    for (int i = 0; i < SCAN_CH; ++i) {
        int idx = base + i;
        if (idx < N) s += deg[idx];
    }
#pragma unroll
    for (int d = 32; d; d >>= 1) s += __shfl_xor(s, d, 64);
    if ((tid & 63) == 0) ws[tid >> 6] = s;
    __syncthreads();
    if (tid == 0) {
        int t = 0;
#pragma unroll
        for (int i = 0; i < SCAN_TPB / 64; ++i) t += ws[i];
        bsum[blockIdx.x] = t;
    }
}
__global__ void scan_out_kernel(const int* __restrict__ deg, const int* __restrict__ bsum, int nsb,
                                int* __restrict__ off, int N, int Etot,
                                const int* __restrict__ tcnt, int* __restrict__ toff, int* __restrict__ tcur,
                                const int* __restrict__ rcnt, int* __restrict__ roff, int* __restrict__ rcur) {
    __shared__ int ts[SCAN_TPB];
    __shared__ int bb;
    int tid = threadIdx.x;
    if (tid < 64) {
        int v = 0;
        if (nsb <= 64) {
            v = (tid < nsb && tid < blockIdx.x) ? bsum[tid] : 0;
#pragma unroll
            for (int d = 32; d; d >>= 1) v += __shfl_xor(v, d, 64);
        } else if (tid == 0) {
            for (int b = 0; b < blockIdx.x; ++b) v += bsum[b];
        }
        if (tid == 0) bb = v;
    }
    if (blockIdx.x == 0 && tid == 1) {
        int a = 0;
        for (int t = 0; t < TT; ++t) { toff[t] = a; tcur[t] = a; a += tcnt[t]; }
        toff[TT] = a;
        int b2 = 0;
        for (int r = 0; r < RR; ++r) { roff[r] = b2; rcur[r] = b2; b2 += rcnt[r]; }
        roff[RR] = b2;
        off[N] = Etot;
    }
    int base = blockIdx.x * SCAN_ELEMS + tid * SCAN_CH;
    int loc[SCAN_CH];
    int s = 0;
#pragma unroll
    for (int i = 0; i < SCAN_CH; ++i) {
        int idx = base + i;
        int v = (idx < N) ? deg[idx] : 0;
        loc[i] = v; s += v;
    }
    ts[tid] = s;
    __syncthreads();
    for (int sh = 1; sh < SCAN_TPB; sh <<= 1) {
        int v = (tid >= sh) ? ts[tid - sh] : 0;
        __syncthreads();
        ts[tid] += v;
        __syncthreads();
    }
    int run = bb + ((tid > 0) ? ts[tid - 1] : 0);
#pragma unroll
    for (int i = 0; i < SCAN_CH; ++i) {
        int idx = base + i;
        if (idx < N) { off[idx] = run; run += loc[i]; }
    }
}

// scatter: pos = offs[d] + erank[e] (no per-edge global atomics); grid-strided.
__global__ void scatter_kernel(const int* __restrict__ src, const int* __restrict__ dst,
                               const int* __restrict__ et, const int* __restrict__ nt,
                               const int* __restrict__ offs, const int* __restrict__ erank,
                               int* __restrict__ tcur, int* __restrict__ rcur,
                               int* __restrict__ rsrc, int* __restrict__ rdst,
                               int* __restrict__ rdpos, int* __restrict__ nidx, int N, int E) {
    __shared__ int l_r[RR], l_t[TT], base_r[RR], base_t[TT];
    if (threadIdx.x < RR) l_r[threadIdx.x] = 0;
    if (threadIdx.x < TT) l_t[threadIdx.x] = 0;
    __syncthreads();
    const int stride = gridDim.x * blockDim.x;
    const int tid = blockIdx.x * blockDim.x + threadIdx.x;
    int s[SCAT_CH], d[SCAT_CH], r[SCAT_CH], rrank[SCAT_CH];
    int t[SCAT_CH], trank[SCAT_CH];
#pragma unroll
    for (int i = 0; i < SCAT_CH; ++i) {
        int e = tid + i * stride;
        if (e < E) {
            s[i] = src[e]; d[i] = dst[e]; r[i] = et[e];
            rrank[i] = atomicAdd(&l_r[r[i]], 1);
        }
        int n = tid + i * stride;
        if (n < N) {
            t[i] = nt[n];
            trank[i] = atomicAdd(&l_t[t[i]], 1);
        }
    }
    __syncthreads();
    if (threadIdx.x < RR)
        base_r[threadIdx.x] = l_r[threadIdx.x] ? atomicAdd(&rcur[threadIdx.x], l_r[threadIdx.x]) : 0;
    if (threadIdx.x < TT)
        base_t[threadIdx.x] = l_t[threadIdx.x] ? atomicAdd(&tcur[threadIdx.x], l_t[threadIdx.x]) : 0;
    __syncthreads();
#pragma unroll
    for (int i = 0; i < SCAT_CH; ++i) {
        int e = tid + i * stride;
        if (e < E) {
            int pos = offs[d[i]] + erank[e];
            int rp = base_r[r[i]] + rrank[i];
            rsrc[rp] = s[i]; rdst[rp] = d[i]; rdpos[rp] = pos;
        }
        int n = tid + i * stride;
        if (n < N) nidx[base_t[t[i]] + trank[i]] = n;
    }
}

// ---------------- node projections ----------------
// a=0: k -> fp16 row (128B); a=1: q -> fp16 row; a=2: v fp16.
// Permuted B cols: lane m's acc holds cols 4m..4m+3 -> one f16x4 store per reg.
__global__ void proj_kernel(const float* __restrict__ h,
                            const float* __restrict__ Wk, const float* __restrict__ Wq,
                            const float* __restrict__ Wv,
                            const int* __restrict__ toff, const int* __restrict__ nidx,
                            _Float16* __restrict__ kh16,
                            _Float16* __restrict__ qout, _Float16* __restrict__ vout) {
    const int t = blockIdx.z, a = blockIdx.y, lane = threadIdx.x;
    const int beg = toff[t], end = toff[t + 1], cnt = end - beg;
    if (cnt <= 0) return;
    const int nstrips = (cnt + 15) >> 4;
    const float* W = (a == 0 ? Wk : (a == 1 ? Wq : Wv)) + (size_t)t * 4096;
    const int m = lane & 15, quad = lane >> 4;

    bf16x8 Bh[2][4], Bl[2][4];
#pragma unroll
    for (int ks = 0; ks < 2; ++ks)
#pragma unroll
        for (int c = 0; c < 4; ++c) load_B_splitp(W, ks, c, lane, Bh[ks][c], Bl[ks][c]);

    _Float16* out = (a == 0) ? kh16 : (a == 1 ? qout : vout);

    for (int s = blockIdx.x; s < nstrips; s += gridDim.x) {
        int base = beg + s * 16;
        int rA = base + m; if (rA > end - 1) rA = end - 1;
        const float* hp = h + (size_t)nidx[rA] * D;
        bf16x8 A0h, A0l, A1h, A1l;
        load_A_split(hp + quad * 8, A0h, A0l);
        load_A_split(hp + 32 + quad * 8, A1h, A1l);
        f32x4 acc[4];
#pragma unroll
        for (int c = 0; c < 4; ++c) acc[c] = (f32x4){0.f, 0.f, 0.f, 0.f};
        SPLIT_MFMA_BODY(acc, A0h, A0l, A1h, A1l, Bh, Bl)
#pragma unroll
        for (int reg = 0; reg < 4; ++reg) {
            int rr = base + quad * 4 + reg;
            if (rr < end) {
                int nid = nidx[rr];
                f16x4 o;
#pragma unroll
                for (int c = 0; c < 4; ++c) o[c] = (_Float16)acc[c][reg];
                *(f16x4*)(out + (size_t)nid * D + m * 4) = o;
            }
        }
    }
}

// ---------------- fused: per-edge scores (x < SCORE_XB) + V2 build (x >= SCORE_XB) ----------------
// score: 2-deep software pipeline (meta s/d/p prefetched 2 strips ahead, k-rows 1 ahead),
// permuted-B q-dot (one f16x4 load per reg), shuffle-distributed rdst/rdpos/rsrc.
__global__ void score_v2_kernel(const int* __restrict__ rsrc, const int* __restrict__ rdst,
                                const int* __restrict__ rdpos, const int* __restrict__ roff,
                                const _Float16* __restrict__ kh16,
                                const _Float16* __restrict__ qn, const float* __restrict__ Aatt,
                                const float* __restrict__ pri, int2* __restrict__ rec,
                                const _Float16* __restrict__ vn, const float* __restrict__ Amsg,
                                _Float16* __restrict__ V2, int N) {
    const int r = blockIdx.y;
    const int lane = threadIdx.x & 63;
    const int wv = threadIdx.x >> 6;
    const int m = lane & 15, quad = lane >> 4;

    if (blockIdx.x >= SCORE_XB) {
        // ---------------- V2 part ----------------
        const int g = (blockIdx.x - SCORE_XB) * 4 + wv;       // 0..V2_XB*4-1
        const int nstrips = (N + 15) >> 4;
        const float* W = Amsg + (size_t)r * 4096;
        f16x8 B[2][4];
#pragma unroll
        for (int ks = 0; ks < 2; ++ks)
#pragma unroll
            for (int c = 0; c < 4; ++c) B[ks][c] = load_B_frag_f16(W, ks, c, lane);

        for (int s = g; s < nstrips; s += V2_XB * 4) {
            int base = s * 16;
            int rA = base + m; if (rA > N - 1) rA = N - 1;
            f16x8 A0 = *(const f16x8*)(vn + (size_t)rA * D + quad * 8);
            f16x8 A1 = *(const f16x8*)(vn + (size_t)rA * D + 32 + quad * 8);
            f32x4 acc[4];
#pragma unroll
            for (int c = 0; c < 4; ++c) acc[c] = (f32x4){0.f, 0.f, 0.f, 0.f};
#pragma unroll
            for (int c = 0; c < 4; ++c) {
                acc[c] = MFMAH(A0, B[0][c], acc[c]);
                acc[c] = MFMAH(A1, B[1][c], acc[c]);
            }
#pragma unroll
            for (int reg = 0; reg < 4; ++reg) {
                int rr = base + quad * 4 + reg;
                if (rr < N) {
                    f16x4 o;
#pragma unroll
                    for (int c = 0; c < 4; ++c) o[c] = (_Float16)acc[c][reg];
                    *(f16x4*)(V2 + ((size_t)rr * RR + r) * D + m * 4) = o;
                }
            }
        }
        return;
    }

    // ---------------- score part ----------------
    const int beg = roff[r], end = roff[r + 1], cnt = end - beg;
    if (cnt <= 0) return;
    const int nstrips = (cnt + 15) >> 4;
    const float scale = pri[r] * 0.125f;
    const float* W = Aatt + (size_t)r * 4096;

    f16x8 Bh[2][4], Bl[2][4];
#pragma unroll
    for (int ks = 0; ks < 2; ++ks)
#pragma unroll
        for (int c = 0; c < 4; ++c) load_B_split_f16(W, ks, c, lane, Bh[ks][c], Bl[ks][c]);

    const int NW = SCORE_XB * 4;
    const int g = blockIdx.x * 4 + wv;                         // 0..NW-1
    if (g >= nstrips) return;

    // pipeline state: current strip's meta+k in regs, next strip's meta in regs
    int sC, dC, pC, sN = 0, dN = 0, pN = 0;
    f16x8 A0, A1;
    {
        int ia = g * 16 + m; if (ia > cnt - 1) ia = cnt - 1;
        sC = rsrc[beg + ia]; dC = rdst[beg + ia]; pC = rdpos[beg + ia];
    }
    {
        const _Float16* kr = kh16 + (size_t)sC * D;
        A0 = *(const f16x8*)(kr + quad * 8);
        A1 = *(const f16x8*)(kr + 32 + quad * 8);
    }
    if (g + NW < nstrips) {
        int ia = (g + NW) * 16 + m; if (ia > cnt - 1) ia = cnt - 1;
        sN = rsrc[beg + ia]; dN = rdst[beg + ia]; pN = rdpos[beg + ia];
    }

    for (int st = g; st < nstrips; st += NW) {
        const int base = st * 16;
        f32x4 acc[4];
#pragma unroll
        for (int c = 0; c < 4; ++c) acc[c] = (f32x4){0.f, 0.f, 0.f, 0.f};
#pragma unroll
        for (int c = 0; c < 4; ++c) {
            acc[c] = MFMAH(A0, Bh[0][c], acc[c]);
            acc[c] = MFMAH(A0, Bl[0][c], acc[c]);
            acc[c] = MFMAH(A1, Bh[1][c], acc[c]);
            acc[c] = MFMAH(A1, Bl[1][c], acc[c]);
        }

        // issue next strip's k-rows (sN arrived >=1 iter ago); latency hides under q-dot
        const bool hN = (st + NW) < nstrips;
        f16x8 A0n, A1n;
        if (hN) {
            const _Float16* kr = kh16 + (size_t)sN * D;
            A0n = *(const f16x8*)(kr + quad * 8);
            A1n = *(const f16x8*)(kr + 32 + quad * 8);
        }
        // issue meta for strip st+2*NW
        int sNN = 0, dNN = 0, pNN = 0;
        const bool hNN = (st + 2 * NW) < nstrips;
        if (hNN) {
            int ia = (st + 2 * NW) * 16 + m; if (ia > cnt - 1) ia = cnt - 1;
            sNN = rsrc[beg + ia]; dNN = rdst[beg + ia]; pNN = rdpos[beg + ia];
        }

        // q-dot: permuted B -> lane m holds cols 4m..4m+3; one f16x4 load per reg
        float p4[4];
#pragma unroll
        for (int reg = 0; reg < 4; ++reg) {
            int dd = __shfl(dC, quad * 4 + reg, 64);
            f16x4 q4 = *(const f16x4*)(qn + (size_t)dd * D + m * 4);
            float pr = acc[0][reg] * (float)q4[0] + acc[1][reg] * (float)q4[1]
                     + acc[2][reg] * (float)q4[2] + acc[3][reg] * (float)q4[3];
#pragma unroll
            for (int d = 8; d; d >>= 1) pr += __shfl_xor(pr, d, 64);
            p4[reg] = pr;
        }
        // write: shuffle src/pos from already-loaded strip meta (all lanes shuffle, m<4 write)
        int wsrc = __shfl(sC, quad * 4 + (m & 3), 64);
        int wpos = __shfl(pC, quad * 4 + (m & 3), 64);
        float wval = ((m & 3) == 0) ? p4[0] : ((m & 3) == 1) ? p4[1] : ((m & 3) == 2) ? p4[2] : p4[3];
        if (m < 4) {
            int idx = base + quad * 4 + m;
            if (idx < cnt) {
                int2 rc;
                rc.x = __float_as_int(wval * scale);
                rc.y = (wsrc << 3) | r;                     // V2 row id
                rec[wpos] = rc;
            }
        }
        // rotate pipeline
        if (hN) {
            A0 = A0n; A1 = A1n;
            sC = sN; dC = dN; pC = pN;
            sN = sNN; dN = dNN; pN = pNN;
        }
    }
}

// ---------------- fused per-dst softmax+aggregation + output transform ----------------
// grid (AGG_XB, T), 256 threads = 16 quads = 16 same-type nodes per strip.
__global__ void agg_out_kernel(const int* __restrict__ offs, const int2* __restrict__ rec,
                               const _Float16* __restrict__ V2,
                               const float* __restrict__ Wa, const float* __restrict__ skp,
                               const int* __restrict__ toff, const int* __restrict__ nidx,
                               float* __restrict__ out) {
    const int t = blockIdx.y;
    const int beg = toff[t], end = toff[t + 1], cnt = end - beg;
    if (cnt <= 0) return;
    const int nstrips = (cnt + 15) >> 4;
    const int lane = threadIdx.x & 63;
    const int wv = threadIdx.x >> 6;          // 4 waves
    const int quad = lane >> 4, ql = lane & 15;
    const int q16 = wv * 4 + quad;            // node slot 0..15
    const int qb = quad << 4;
    const int m = lane & 15, qd = lane >> 4;  // MFMA roles
    const float sg = 1.f / (1.f + __expf(-skp[t]));

    __shared__ float As[16][68];              // padded stride breaks LDS bank conflicts

    // per-wave B slice (c = wv): canonical cols (scalar f32 out stores stay coalesced)
    bf16x8 Bh2[2], Bl2[2];
    const float* W = Wa + (size_t)t * 4096;
#pragma unroll
    for (int ks = 0; ks < 2; ++ks) load_B_split(W, ks, wv, lane, Bh2[ks], Bl2[ks]);

    for (int s = blockIdx.x; s < nstrips; s += gridDim.x) {
        int base = beg + s * 16;
        int rr = base + q16; if (rr > end - 1) rr = end - 1;   // tail: duplicate last node
        int i = nidx[rr];
        // ---- aggregation for node i (one quad) ----
        const int ebeg = offs[i], eend = offs[i + 1];
        float mmax = -INFINITY, lsum = 0.f;
        float a0 = 0.f, a1 = 0.f, a2 = 0.f, a3 = 0.f;
        for (int cs = ebeg; cs < eend; cs += 16) {
            int cl = eend - cs; if (cl > 16) cl = 16;
            int2 rc; rc.y = 0;
            float sc = -INFINITY;
            if (ql < cl) { rc = rec[cs + ql]; sc = __int_as_float(rc.x); }
            float cm = sc;
#pragma unroll
            for (int d = 8; d; d >>= 1) cm = fmaxf(cm, __shfl_xor(cm, d, 64));
            float mn = fmaxf(mmax, cm);
            float cf = __expf(mmax - mn);
            float ex = (ql < cl) ? __expf(sc - mn) : 0.f;
            float csum = ex;
#pragma unroll
            for (int d = 8; d; d >>= 1) csum += __shfl_xor(csum, d, 64);
            lsum = lsum * cf + csum;
            a0 *= cf; a1 *= cf; a2 *= cf; a3 *= cf;
            for (int e = 0; e < cl; e += 4) {
                float w0 = __shfl(ex, qb + e, 64),     w1 = __shfl(ex, qb + e + 1, 64);
                float w2 = __shfl(ex, qb + e + 2, 64), w3 = __shfl(ex, qb + e + 3, 64);
                int   i0 = __shfl(rc.y, qb + e, 64),     i1 = __shfl(rc.y, qb + e + 1, 64);
                int   i2 = __shfl(rc.y, qb + e + 2, 64), i3 = __shfl(rc.y, qb + e + 3, 64);
                f16x4 v0 = *(const f16x4*)(V2 + (size_t)i0 * D + ql * 4);
                f16x4 v1 = *(const f16x4*)(V2 + (size_t)i1 * D + ql * 4);
                f16x4 v2 = *(const f16x4*)(V2 + (size_t)i2 * D + ql * 4);
                f16x4 v3 = *(const f16x4*)(V2 + (size_t)i3 * D + ql * 4);
                a0 += w0 * (float)v0[0] + w1 * (float)v1[0] + w2 * (float)v2[0] + w3 * (float)v3[0];
                a1 += w0 * (float)v0[1] + w1 * (float)v1[1] + w2 * (float)v2[1] + w3 * (float)v3[1];
                a2 += w0 * (float)v0[2] + w1 * (float)v1[2] + w2 * (float)v2[2] + w3 * (float)v3[2];
                a3 += w0 * (float)v0[3] + w1 * (float)v1[3] + w2 * (float)v2[3] + w3 * (float)v3[3];
            }
            mmax = mn;
        }
        float inv = 1.f / (lsum + 1e-16f);
        As[q16][ql * 4 + 0] = a0 * inv;
        As[q16][ql * 4 + 1] = a1 * inv;
        As[q16][ql * 4 + 2] = a2 * inv;
        As[q16][ql * 4 + 3] = a3 * inv;
        __syncthreads();

        // ---- out transform: each wave computes its 16-col slice (identical MFMA seq) ----
        bf16x8 A0h, A0l, A1h, A1l;
        load_A_split(&As[m][qd * 8], A0h, A0l);
        load_A_split(&As[m][32 + qd * 8], A1h, A1l);
        f32x4 acc = (f32x4){0.f, 0.f, 0.f, 0.f};
        acc = MFMA16(A0h, Bh2[0], acc);
        acc = MFMA16(A0l, Bh2[0], acc);
        acc = MFMA16(A0h, Bl2[0], acc);
        acc = MFMA16(A1h, Bh2[1], acc);
        acc = MFMA16(A1l, Bh2[1], acc);
        acc = MFMA16(A1h, Bl2[1], acc);
#pragma unroll
        for (int reg = 0; reg < 4; ++reg) {
            int rrr = base + qd * 4 + reg;
            if (rrr < end)
                out[(size_t)nidx[rrr] * D + wv * 16 + m] = acc[reg] * sg;
        }
        __syncthreads();   // protect As before next strip
    }
}

// ---------------- launch ----------------
extern "C" void kernel_launch(void* const* d_in, const int* in_sizes, int n_in,
                              void* d_out, int out_size, void* d_ws, size_t ws_size,
                              hipStream_t stream) {
    const float* h     = (const float*)d_in[0];
    const int*   adj   = (const int*)d_in[1];     // [2,E]: src row then dst row
    const int*   etype = (const int*)d_in[2];
    const int*   ntype = (const int*)d_in[3];
    const float* Wk    = (const float*)d_in[6];
    const float* Wq    = (const float*)d_in[7];
    const float* Wv    = (const float*)d_in[8];
    const float* Wa    = (const float*)d_in[9];
    const float* pri   = (const float*)d_in[10];
    const float* Aatt  = (const float*)d_in[11];
    const float* Amsg  = (const float*)d_in[12];
    const float* skp   = (const float*)d_in[13];
    const int N = in_sizes[3];
    const int E = in_sizes[2];
    float* out = (float*)d_out;

    char* w = (char*)d_ws;
    auto alloc = [&](size_t b) { char* p = w; w += (b + 255) & ~(size_t)255; return p; };
    _Float16* kh16 = (_Float16*)alloc((size_t)N * D * 2);
    _Float16* qn   = (_Float16*)alloc((size_t)N * D * 2);
    _Float16* vn   = (_Float16*)alloc((size_t)N * D * 2);
    _Float16* V2   = (_Float16*)alloc((size_t)N * RR * D * 2);
    int* deg  = (int*)alloc((size_t)(N + 16) * 4);
    int* tcnt = deg + N;
    int* rcnt = deg + N + 8;
    int* offs = (int*)alloc((size_t)(N + 1) * 4);
    int* erank = (int*)alloc((size_t)E * 4);
    int* toff = (int*)alloc(64);
    int* tcur = (int*)alloc(64);
    int* roff = (int*)alloc(64);
    int* rcur = (int*)alloc(64);
    int2* rec = (int2*)alloc((size_t)E * 8);
    int* rsrc  = (int*)alloc((size_t)E * 4);
    int* rdst  = (int*)alloc((size_t)E * 4);
    int* rdpos = (int*)alloc((size_t)E * 4);
    int* nidx  = (int*)alloc((size_t)N * 4);
    const int nsb = (N + SCAN_ELEMS - 1) / SCAN_ELEMS;
    int* bsum  = (int*)alloc((size_t)nsb * 4);

    (void)hipMemsetAsync(deg, 0, (size_t)(N + 16) * 4, stream);

    const int degBlocks = (E + 256 * DEG_CH - 1) / (256 * DEG_CH);
    deg_kernel<<<degBlocks, 256, 0, stream>>>(adj + E, deg, erank, E);
    typehist_kernel<<<128, 256, 0, stream>>>(etype, ntype, rcnt, tcnt, N, E);
    scan_sum_kernel<<<nsb, SCAN_TPB, 0, stream>>>(deg, bsum, N);
    scan_out_kernel<<<nsb, SCAN_TPB, 0, stream>>>(deg, bsum, nsb, offs, N, E,
                                                  tcnt, toff, tcur, rcnt, roff, rcur);
    const int mx = (E > N ? E : N);
    const int scatBlocks = (mx + 256 * SCAT_CH - 1) / (256 * SCAT_CH);
    scatter_kernel<<<scatBlocks, 256, 0, stream>>>(adj, adj + E, etype, ntype,
                                                   offs, erank, tcur, rcur,
                                                   rsrc, rdst, rdpos, nidx, N, E);
    proj_kernel<<<dim3(128, 3, TT), 64, 0, stream>>>(h, Wk, Wq, Wv, toff, nidx, kh16, qn, vn);
    score_v2_kernel<<<dim3(SCORE_XB + V2_XB, RR), 256, 0, stream>>>(rsrc, rdst, rdpos, roff,
                                                                    kh16, qn, Aatt, pri, rec,
                                                                    vn, Amsg, V2, N);
    agg_out_kernel<<<dim3(AGG_XB, TT), 256, 0, stream>>>(offs, rec, V2, Wa, skp, toff, nidx, out);
}

// Round 7
// 242.100 us; speedup vs baseline: 1.0853x; 1.0853x over previous
//
#include <hip/hip_runtime.h>
#include <math.h>

typedef float f32x4 __attribute__((ext_vector_type(4)));
typedef short bf16x8 __attribute__((ext_vector_type(8)));
typedef _Float16 f16x8 __attribute__((ext_vector_type(8)));
typedef _Float16 f16x4 __attribute__((ext_vector_type(4)));

#define D 64
#define TT 8
#define RR 8

#define SCAN_TPB 256
#define SCAN_CH 4
#define SCAN_ELEMS (SCAN_TPB * SCAN_CH)   // 1024 elements per block

#define MAXBINS 256      // dst-bin = 256 nodes; supports N <= 65536
#define NBLK1 784        // p1 grid; must be identical in p1_hist and p1_scat (matrix indexed by block)
#define QXB 128          // v2q2 x-blocks per relation
#define SCORE_BLOCKS 2048
#define AGG_XB 256       // agg_out x-blocks per type

// ---------------- scalar helpers ----------------
__device__ __forceinline__ float bf2f(unsigned short u) {
    union { unsigned int i; float f; } x;
    x.i = ((unsigned int)u) << 16;
    return x.f;
}
__device__ __forceinline__ unsigned short f2bf(float f) {
    union { float f; unsigned int i; } x;
    x.f = f;
    unsigned int i = x.i;
    unsigned int r = (i + 0x7FFFu + ((i >> 16) & 1u)) >> 16;   // RNE
    return (unsigned short)r;
}
struct BfPair { short hi; short lo; };
__device__ __forceinline__ BfPair split2(float x) {
    BfPair p;
    unsigned short h = f2bf(x);
    p.hi = (short)h;
    p.lo = (short)f2bf(x - bf2f(h));
    return p;
}
__device__ __forceinline__ void load_A_split(const float* __restrict__ p, bf16x8& ah, bf16x8& al) {
#pragma unroll
    for (int i = 0; i < 8; ++i) {
        BfPair s = split2(p[i]);
        ah[i] = s.hi; al[i] = s.lo;
    }
}
// bf16 split B fragment, canonical cols (agg_out: col = c*16+n)
__device__ __forceinline__ void load_B_split(const float* __restrict__ W, int ks, int c, int lane,
                                             bf16x8& bh, bf16x8& bl) {
    int n = lane & 15, q = lane >> 4;
#pragma unroll
    for (int i = 0; i < 8; ++i) {
        BfPair s = split2(W[(ks * 32 + q * 8 + i) * 64 + c * 16 + n]);
        bh[i] = s.hi; bl[i] = s.lo;
    }
}
// bf16 split B fragment, PERMUTED cols (proj: col = n*4+c; store address carries the
// permutation so kh16/qn/vn memory layout stays natural feature order)
__device__ __forceinline__ void load_B_splitp(const float* __restrict__ W, int ks, int c, int lane,
                                              bf16x8& bh, bf16x8& bl) {
    int n = lane & 15, q = lane >> 4;
#pragma unroll
    for (int i = 0; i < 8; ++i) {
        BfPair s = split2(W[(ks * 32 + q * 8 + i) * 64 + n * 4 + c]);
        bh[i] = s.hi; bl[i] = s.lo;
    }
}

#define MFMA16(a, b, c) __builtin_amdgcn_mfma_f32_16x16x32_bf16(a, b, c, 0, 0, 0)
#define MFMAH(a, b, c)  __builtin_amdgcn_mfma_f32_16x16x32_f16(a, b, c, 0, 0, 0)

// 24 bf16 MFMAs: acc += (Ah+Al)@(Bh+Bl) dropping lo*lo
#define SPLIT_MFMA_BODY(acc, A0h, A0l, A1h, A1l, Bh, Bl)          \
    _Pragma("unroll")                                             \
    for (int c = 0; c < 4; ++c) {                                 \
        acc[c] = MFMA16(A0h, Bh[0][c], acc[c]);                   \
        acc[c] = MFMA16(A0l, Bh[0][c], acc[c]);                   \
        acc[c] = MFMA16(A0h, Bl[0][c], acc[c]);                   \
        acc[c] = MFMA16(A1h, Bh[1][c], acc[c]);                   \
        acc[c] = MFMA16(A1l, Bh[1][c], acc[c]);                   \
        acc[c] = MFMA16(A1h, Bl[1][c], acc[c]);                   \
    }

// ---------------- atomic-free CSR build (two-level counting sort by dst) ----------------
// p1_hist: per-block LDS histogram over dst>>8 bins -> matrix mat[bin][blk]. No global
// per-edge atomics (r1's mistake was per-edge GLOBAL bin atomics). Also type-histogram.
__global__ void p1_hist_kernel(const int* __restrict__ dst, const int* __restrict__ nt,
                               int* __restrict__ mat, int* __restrict__ tcnt,
                               int N, int E, int nbins) {
    __shared__ int c[MAXBINS];
    __shared__ int lt[TT];
    if (threadIdx.x < MAXBINS) c[threadIdx.x] = 0;
    if (threadIdx.x < TT) lt[threadIdx.x] = 0;
    __syncthreads();
    const int stride = gridDim.x * blockDim.x;
    for (int e = blockIdx.x * blockDim.x + threadIdx.x; e < E; e += stride)
        atomicAdd(&c[dst[e] >> 8], 1);
    for (int n = blockIdx.x * blockDim.x + threadIdx.x; n < N; n += stride)
        atomicAdd(&lt[nt[n]], 1);
    __syncthreads();
    if (threadIdx.x < nbins) mat[threadIdx.x * gridDim.x + blockIdx.x] = c[threadIdx.x];
    if (threadIdx.x < TT && lt[threadIdx.x]) atomicAdd(&tcnt[threadIdx.x], lt[threadIdx.x]);
}

// ---- 2-phase device-wide exclusive scan (generic length) ----
__global__ void scan_sum_kernel(const int* __restrict__ deg, int* __restrict__ bsum, int N) {
    __shared__ int ws[SCAN_TPB / 64];
    int tid = threadIdx.x;
    int base = blockIdx.x * SCAN_ELEMS + tid * SCAN_CH;
    int s = 0;
#pragma unroll
    for (int i = 0; i < SCAN_CH; ++i) {
        int idx = base + i;
        if (idx < N) s += deg[idx];
    }
#pragma unroll
    for (int d = 32; d; d >>= 1) s += __shfl_xor(s, d, 64);
    if ((tid & 63) == 0) ws[tid >> 6] = s;
    __syncthreads();
    if (tid == 0) {
        int t = 0;
#pragma unroll
        for (int i = 0; i < SCAN_TPB / 64; ++i) t += ws[i];
        bsum[blockIdx.x] = t;
    }
}
__global__ void scan_out_kernel(const int* __restrict__ deg, const int* __restrict__ bsum, int nsb,
                                int* __restrict__ off, int N, int Etot,
                                const int* __restrict__ tcnt, int* __restrict__ toff, int* __restrict__ tcur) {
    __shared__ int ts[SCAN_TPB];
    __shared__ int bb;
    int tid = threadIdx.x;
    if (tid < 64) {
        int v = 0;
        if (nsb <= 64) {
            v = (tid < nsb && tid < blockIdx.x) ? bsum[tid] : 0;
#pragma unroll
            for (int d = 32; d; d >>= 1) v += __shfl_xor(v, d, 64);
        } else if (tid == 0) {
            for (int b = 0; b < blockIdx.x; ++b) v += bsum[b];
        }
        if (tid == 0) bb = v;
    }
    if (blockIdx.x == 0 && tid == 1) {
        int a = 0;
        for (int t = 0; t < TT; ++t) { toff[t] = a; tcur[t] = a; a += tcnt[t]; }
        toff[TT] = a;
        off[N] = Etot;
    }
    int base = blockIdx.x * SCAN_ELEMS + tid * SCAN_CH;
    int loc[SCAN_CH];
    int s = 0;
#pragma unroll
    for (int i = 0; i < SCAN_CH; ++i) {
        int idx = base + i;
        int v = (idx < N) ? deg[idx] : 0;
        loc[i] = v; s += v;
    }
    ts[tid] = s;
    __syncthreads();
    for (int sh = 1; sh < SCAN_TPB; sh <<= 1) {
        int v = (tid >= sh) ? ts[tid - sh] : 0;
        __syncthreads();
        ts[tid] += v;
        __syncthreads();
    }
    int run = bb + ((tid > 0) ? ts[tid - 1] : 0);
#pragma unroll
    for (int i = 0; i < SCAN_CH; ++i) {
        int idx = base + i;
        if (idx < N) { off[idx] = run; run += loc[i]; }
    }
}

// p1_scat: scatter edges to their bin chunk (base from scanned matrix + fresh LDS ranks;
// same edge->block mapping as p1_hist so counts match). Also builds type-grouped nidx
// (single-shot: NBLK1*256 >= N).
__global__ void p1_scat_kernel(const int* __restrict__ src, const int* __restrict__ dst,
                               const int* __restrict__ et, const int* __restrict__ nt,
                               const int* __restrict__ moffs, int* __restrict__ tcur,
                               int2* __restrict__ S, int* __restrict__ nidx, int N, int E) {
    __shared__ int c[MAXBINS];
    __shared__ int lt[TT], bt[TT];
    if (threadIdx.x < MAXBINS) c[threadIdx.x] = 0;
    if (threadIdx.x < TT) lt[threadIdx.x] = 0;
    __syncthreads();
    const int n = blockIdx.x * blockDim.x + threadIdx.x;
    int t = 0, trank = 0;
    if (n < N) { t = nt[n]; trank = atomicAdd(&lt[t], 1); }
    const int stride = gridDim.x * blockDim.x;
    for (int e = blockIdx.x * blockDim.x + threadIdx.x; e < E; e += stride) {
        int d = dst[e];
        int b = d >> 8;
        int rk = atomicAdd(&c[b], 1);
        int pos = moffs[b * gridDim.x + blockIdx.x] + rk;
        int2 s2; s2.x = src[e]; s2.y = (d << 3) | et[e];
        S[pos] = s2;
    }
    __syncthreads();
    if (threadIdx.x < TT)
        bt[threadIdx.x] = lt[threadIdx.x] ? atomicAdd(&tcur[threadIdx.x], lt[threadIdx.x]) : 0;
    __syncthreads();
    if (n < N) nidx[bt[t] + trank] = n;
}

// p2: one block per 256-dst bin; LDS counting sort by dst -> final dst-CSR meta M + offs.
// Within-dst order is arbitrary (matches original erank semantics).
__global__ void p2_sort_kernel(const int2* __restrict__ S, const int* __restrict__ moffs,
                               int* __restrict__ offs, int2* __restrict__ M,
                               int N, int E, int nblk1) {
    const int b = blockIdx.x, tid = threadIdx.x;
    const int A1 = moffs[b * nblk1];
    const int A2 = moffs[(b + 1) * nblk1];
    __shared__ int dc[MAXBINS], ds[MAXBINS], dr[MAXBINS];
    dc[tid] = 0; dr[tid] = 0;
    __syncthreads();
    for (int e = A1 + tid; e < A2; e += blockDim.x)
        atomicAdd(&dc[(S[e].y >> 3) & 255], 1);
    __syncthreads();
    int v = dc[tid];
    ds[tid] = v;
    __syncthreads();
    for (int sh = 1; sh < MAXBINS; sh <<= 1) {
        int u = (tid >= sh) ? ds[tid - sh] : 0;
        __syncthreads();
        ds[tid] += u;
        __syncthreads();
    }
    int excl = tid ? ds[tid - 1] : 0;
    int node = b * 256 + tid;
    if (node < N) offs[node] = A1 + excl;
    dc[tid] = excl;                        // counts no longer needed; keep excl in LDS
    __syncthreads();
    for (int e = A1 + tid; e < A2; e += blockDim.x) {
        int2 s2 = S[e];
        int dl = (s2.y >> 3) & 255;
        int rk = atomicAdd(&dr[dl], 1);
        M[A1 + dc[dl] + rk] = s2;
    }
    if (b == 0 && tid == 0) offs[N] = E;
}

// ---------------- node projections (unchanged) ----------------
__global__ void proj_kernel(const float* __restrict__ h,
                            const float* __restrict__ Wk, const float* __restrict__ Wq,
                            const float* __restrict__ Wv,
                            const int* __restrict__ toff, const int* __restrict__ nidx,
                            _Float16* __restrict__ kh16,
                            _Float16* __restrict__ qout, _Float16* __restrict__ vout) {
    const int t = blockIdx.z, a = blockIdx.y, lane = threadIdx.x;
    const int beg = toff[t], end = toff[t + 1], cnt = end - beg;
    if (cnt <= 0) return;
    const int nstrips = (cnt + 15) >> 4;
    const float* W = (a == 0 ? Wk : (a == 1 ? Wq : Wv)) + (size_t)t * 4096;
    const int m = lane & 15, quad = lane >> 4;

    bf16x8 Bh[2][4], Bl[2][4];
#pragma unroll
    for (int ks = 0; ks < 2; ++ks)
#pragma unroll
        for (int c = 0; c < 4; ++c) load_B_splitp(W, ks, c, lane, Bh[ks][c], Bl[ks][c]);

    _Float16* out = (a == 0) ? kh16 : (a == 1 ? qout : vout);

    for (int s = blockIdx.x; s < nstrips; s += gridDim.x) {
        int base = beg + s * 16;
        int rA = base + m; if (rA > end - 1) rA = end - 1;
        const float* hp = h + (size_t)nidx[rA] * D;
        bf16x8 A0h, A0l, A1h, A1l;
        load_A_split(hp + quad * 8, A0h, A0l);
        load_A_split(hp + 32 + quad * 8, A1h, A1l);
        f32x4 acc[4];
#pragma unroll
        for (int c = 0; c < 4; ++c) acc[c] = (f32x4){0.f, 0.f, 0.f, 0.f};
        SPLIT_MFMA_BODY(acc, A0h, A0l, A1h, A1l, Bh, Bl)
#pragma unroll
        for (int reg = 0; reg < 4; ++reg) {
            int rr = base + quad * 4 + reg;
            if (rr < end) {
                int nid = nidx[rr];
                f16x4 o;
#pragma unroll
                for (int c = 0; c < 4; ++c) o[c] = (_Float16)acc[c][reg];
                *(f16x4*)(out + (size_t)nid * D + m * 4) = o;
            }
        }
    }
}

// ---------------- V2 + Q2 build ----------------
// V2[s*8+r] = vn[s] @ Amsg_r          (as before, f16)
// Q2[d*8+r] = (Aatt_r @ qn[d]) * pri_r/8   (A^T fragment, scale folded; row id == (d<<3)|r)
__global__ void v2q2_kernel(const _Float16* __restrict__ vn, const _Float16* __restrict__ qn,
                            const float* __restrict__ Amsg, const float* __restrict__ Aatt,
                            const float* __restrict__ pri,
                            _Float16* __restrict__ V2, _Float16* __restrict__ Q2, int N) {
    const int r = blockIdx.y;
    const int lane = threadIdx.x & 63;
    const int wv = threadIdx.x >> 6;
    const int m = lane & 15, quad = lane >> 4;
    const int g = blockIdx.x * 4 + wv;
    const int nstrips = (N + 15) >> 4;
    const float scale = pri[r] * 0.125f;
    const float* Wv = Amsg + (size_t)r * 4096;
    const float* Wq = Aatt + (size_t)r * 4096;

    f16x8 Bv[2][4], Bq[2][4];
    {
        const int n = lane & 15, q = lane >> 4;
#pragma unroll
        for (int ks = 0; ks < 2; ++ks)
#pragma unroll
            for (int c = 0; c < 4; ++c) {
                f16x8 bv, bq;
#pragma unroll
                for (int i = 0; i < 8; ++i) {
                    int kk = ks * 32 + q * 8 + i;
                    int col = n * 4 + c;                       // permuted col (matches f16x4 store addr)
                    bv[i] = (_Float16)Wv[kk * 64 + col];
                    bq[i] = (_Float16)(Wq[col * 64 + kk] * scale);   // A^T, scale folded
                }
                Bv[ks][c] = bv; Bq[ks][c] = bq;
            }
    }

    for (int s = g; s < nstrips; s += QXB * 4) {
        int base = s * 16;
        int rA = base + m; if (rA > N - 1) rA = N - 1;
        // V2 from vn
        {
            f16x8 A0 = *(const f16x8*)(vn + (size_t)rA * D + quad * 8);
            f16x8 A1 = *(const f16x8*)(vn + (size_t)rA * D + 32 + quad * 8);
            f32x4 acc[4];
#pragma unroll
            for (int c = 0; c < 4; ++c) acc[c] = (f32x4){0.f, 0.f, 0.f, 0.f};
#pragma unroll
            for (int c = 0; c < 4; ++c) {
                acc[c] = MFMAH(A0, Bv[0][c], acc[c]);
                acc[c] = MFMAH(A1, Bv[1][c], acc[c]);
            }
#pragma unroll
            for (int reg = 0; reg < 4; ++reg) {
                int rr = base + quad * 4 + reg;
                if (rr < N) {
                    f16x4 o;
#pragma unroll
                    for (int c = 0; c < 4; ++c) o[c] = (_Float16)acc[c][reg];
                    *(f16x4*)(V2 + ((size_t)rr * RR + r) * D + m * 4) = o;
                }
            }
        }
        // Q2 from qn
        {
            f16x8 A0 = *(const f16x8*)(qn + (size_t)rA * D + quad * 8);
            f16x8 A1 = *(const f16x8*)(qn + (size_t)rA * D + 32 + quad * 8);
            f32x4 acc[4];
#pragma unroll
            for (int c = 0; c < 4; ++c) acc[c] = (f32x4){0.f, 0.f, 0.f, 0.f};
#pragma unroll
            for (int c = 0; c < 4; ++c) {
                acc[c] = MFMAH(A0, Bq[0][c], acc[c]);
                acc[c] = MFMAH(A1, Bq[1][c], acc[c]);
            }
#pragma unroll
            for (int reg = 0; reg < 4; ++reg) {
                int rr = base + quad * 4 + reg;
                if (rr < N) {
                    f16x4 o;
#pragma unroll
                    for (int c = 0; c < 4; ++c) o[c] = (_Float16)acc[c][reg];
                    *(f16x4*)(Q2 + ((size_t)rr * RR + r) * D + m * 4) = o;
                }
            }
        }
    }
}

// ---------------- per-edge scores ----------------
// Edges dst-sorted: meta M sequential, rec sequential, Q2 gathers dst-window-local,
// k gathers random over 6.4MB (as before). Per lane: one edge, 16x16B loads + 64-term dot.
__global__ void score_kernel(const int2* __restrict__ M, const _Float16* __restrict__ kh16,
                             const _Float16* __restrict__ Q2, int2* __restrict__ rec, int E) {
    const int stride = gridDim.x * blockDim.x;
    for (int e = blockIdx.x * blockDim.x + threadIdx.x; e < E; e += stride) {
        int2 md = M[e];                                    // {src, (dst<<3)|et}
        const _Float16* kr = kh16 + (size_t)md.x * D;
        const _Float16* qr = Q2 + (size_t)md.y * D;        // row id == (dst<<3)|et
        float acc = 0.f;
#pragma unroll
        for (int j = 0; j < 8; ++j) {
            f16x8 kk = *(const f16x8*)(kr + j * 8);
            f16x8 qq = *(const f16x8*)(qr + j * 8);
#pragma unroll
            for (int u = 0; u < 8; ++u) acc += (float)kk[u] * (float)qq[u];
        }
        int2 rc;
        rc.x = __float_as_int(acc);                        // scale folded into Q2
        rc.y = (md.x << 3) | (md.y & 7);                   // V2 row id
        rec[e] = rc;
    }
}

// ---------------- fused per-dst softmax+aggregation + output transform (unchanged) ----------------
__global__ void agg_out_kernel(const int* __restrict__ offs, const int2* __restrict__ rec,
                               const _Float16* __restrict__ V2,
                               const float* __restrict__ Wa, const float* __restrict__ skp,
                               const int* __restrict__ toff, const int* __restrict__ nidx,
                               float* __restrict__ out) {
    const int t = blockIdx.y;
    const int beg = toff[t], end = toff[t + 1], cnt = end - beg;
    if (cnt <= 0) return;
    const int nstrips = (cnt + 15) >> 4;
    const int lane = threadIdx.x & 63;
    const int wv = threadIdx.x >> 6;          // 4 waves
    const int quad = lane >> 4, ql = lane & 15;
    const int q16 = wv * 4 + quad;            // node slot 0..15
    const int qb = quad << 4;
    const int m = lane & 15, qd = lane >> 4;  // MFMA roles
    const float sg = 1.f / (1.f + __expf(-skp[t]));

    __shared__ float As[16][68];              // padded stride breaks LDS bank conflicts

    bf16x8 Bh2[2], Bl2[2];
    const float* W = Wa + (size_t)t * 4096;
#pragma unroll
    for (int ks = 0; ks < 2; ++ks) load_B_split(W, ks, wv, lane, Bh2[ks], Bl2[ks]);

    for (int s = blockIdx.x; s < nstrips; s += gridDim.x) {
        int base = beg + s * 16;
        int rr = base + q16; if (rr > end - 1) rr = end - 1;   // tail: duplicate last node
        int i = nidx[rr];
        const int ebeg = offs[i], eend = offs[i + 1];
        float mmax = -INFINITY, lsum = 0.f;
        float a0 = 0.f, a1 = 0.f, a2 = 0.f, a3 = 0.f;
        for (int cs = ebeg; cs < eend; cs += 16) {
            int cl = eend - cs; if (cl > 16) cl = 16;
            int2 rc; rc.y = 0;
            float sc = -INFINITY;
            if (ql < cl) { rc = rec[cs + ql]; sc = __int_as_float(rc.x); }
            float cm = sc;
#pragma unroll
            for (int d = 8; d; d >>= 1) cm = fmaxf(cm, __shfl_xor(cm, d, 64));
            float mn = fmaxf(mmax, cm);
            float cf = __expf(mmax - mn);
            float ex = (ql < cl) ? __expf(sc - mn) : 0.f;
            float csum = ex;
#pragma unroll
            for (int d = 8; d; d >>= 1) csum += __shfl_xor(csum, d, 64);
            lsum = lsum * cf + csum;
            a0 *= cf; a1 *= cf; a2 *= cf; a3 *= cf;
            for (int e = 0; e < cl; e += 4) {
                float w0 = __shfl(ex, qb + e, 64),     w1 = __shfl(ex, qb + e + 1, 64);
                float w2 = __shfl(ex, qb + e + 2, 64), w3 = __shfl(ex, qb + e + 3, 64);
                int   i0 = __shfl(rc.y, qb + e, 64),     i1 = __shfl(rc.y, qb + e + 1, 64);
                int   i2 = __shfl(rc.y, qb + e + 2, 64), i3 = __shfl(rc.y, qb + e + 3, 64);
                f16x4 v0 = *(const f16x4*)(V2 + (size_t)i0 * D + ql * 4);
                f16x4 v1 = *(const f16x4*)(V2 + (size_t)i1 * D + ql * 4);
                f16x4 v2 = *(const f16x4*)(V2 + (size_t)i2 * D + ql * 4);
                f16x4 v3 = *(const f16x4*)(V2 + (size_t)i3 * D + ql * 4);
                a0 += w0 * (float)v0[0] + w1 * (float)v1[0] + w2 * (float)v2[0] + w3 * (float)v3[0];
                a1 += w0 * (float)v0[1] + w1 * (float)v1[1] + w2 * (float)v2[1] + w3 * (float)v3[1];
                a2 += w0 * (float)v0[2] + w1 * (float)v1[2] + w2 * (float)v2[2] + w3 * (float)v3[2];
                a3 += w0 * (float)v0[3] + w1 * (float)v1[3] + w2 * (float)v2[3] + w3 * (float)v3[3];
            }
            mmax = mn;
        }
        float inv = 1.f / (lsum + 1e-16f);
        As[q16][ql * 4 + 0] = a0 * inv;
        As[q16][ql * 4 + 1] = a1 * inv;
        As[q16][ql * 4 + 2] = a2 * inv;
        As[q16][ql * 4 + 3] = a3 * inv;
        __syncthreads();

        bf16x8 A0h, A0l, A1h, A1l;
        load_A_split(&As[m][qd * 8], A0h, A0l);
        load_A_split(&As[m][32 + qd * 8], A1h, A1l);
        f32x4 acc = (f32x4){0.f, 0.f, 0.f, 0.f};
        acc = MFMA16(A0h, Bh2[0], acc);
        acc = MFMA16(A0l, Bh2[0], acc);
        acc = MFMA16(A0h, Bl2[0], acc);
        acc = MFMA16(A1h, Bh2[1], acc);
        acc = MFMA16(A1l, Bh2[1], acc);
        acc = MFMA16(A1h, Bl2[1], acc);
#pragma unroll
        for (int reg = 0; reg < 4; ++reg) {
            int rrr = base + qd * 4 + reg;
            if (rrr < end)
                out[(size_t)nidx[rrr] * D + wv * 16 + m] = acc[reg] * sg;
        }
        __syncthreads();   // protect As before next strip
    }
}

// ---------------- launch ----------------
extern "C" void kernel_launch(void* const* d_in, const int* in_sizes, int n_in,
                              void* d_out, int out_size, void* d_ws, size_t ws_size,
                              hipStream_t stream) {
    const float* h     = (const float*)d_in[0];
    const int*   adj   = (const int*)d_in[1];     // [2,E]: src row then dst row
    const int*   etype = (const int*)d_in[2];
    const int*   ntype = (const int*)d_in[3];
    const float* Wk    = (const float*)d_in[6];
    const float* Wq    = (const float*)d_in[7];
    const float* Wv    = (const float*)d_in[8];
    const float* Wa    = (const float*)d_in[9];
    const float* pri   = (const float*)d_in[10];
    const float* Aatt  = (const float*)d_in[11];
    const float* Amsg  = (const float*)d_in[12];
    const float* skp   = (const float*)d_in[13];
    const int N = in_sizes[3];
    const int E = in_sizes[2];
    float* out = (float*)d_out;

    const int nbins = (N + 255) >> 8;             // 256-node dst bins (N <= 65536)
    const int Nscan = nbins * NBLK1;              // matrix length for the scan
    const int nsb = (Nscan + SCAN_ELEMS - 1) / SCAN_ELEMS;

    char* w = (char*)d_ws;
    auto alloc = [&](size_t b) { char* p = w; w += (b + 255) & ~(size_t)255; return p; };
    _Float16* kh16 = (_Float16*)alloc((size_t)N * D * 2);
    _Float16* qn   = (_Float16*)alloc((size_t)N * D * 2);
    _Float16* vn   = (_Float16*)alloc((size_t)N * D * 2);
    _Float16* V2   = (_Float16*)alloc((size_t)N * RR * D * 2);
    _Float16* Q2   = (_Float16*)alloc((size_t)N * RR * D * 2);
    int2* S   = (int2*)alloc((size_t)E * 8);      // bin-sorted meta; DEAD after p2 -> rec aliases it
    int2* M   = (int2*)alloc((size_t)E * 8);      // dst-sorted meta
    int2* rec = S;                                // alias: S consumed by p2 before score writes rec
    int* mat   = (int*)alloc((size_t)Nscan * 4);
    int* moffs = (int*)alloc((size_t)(Nscan + 1) * 4);
    int* bsum  = (int*)alloc((size_t)nsb * 4);
    int* offs  = (int*)alloc((size_t)(N + 1) * 4);
    int* nidx  = (int*)alloc((size_t)N * 4);
    int* tcnt  = (int*)alloc(64);
    int* tcur  = (int*)alloc(64);
    int* toff  = (int*)alloc(64);

    (void)hipMemsetAsync(tcnt, 0, 32, stream);

    p1_hist_kernel<<<NBLK1, 256, 0, stream>>>(adj + E, ntype, mat, tcnt, N, E, nbins);
    scan_sum_kernel<<<nsb, SCAN_TPB, 0, stream>>>(mat, bsum, Nscan);
    scan_out_kernel<<<nsb, SCAN_TPB, 0, stream>>>(mat, bsum, nsb, moffs, Nscan, E,
                                                  tcnt, toff, tcur);
    p1_scat_kernel<<<NBLK1, 256, 0, stream>>>(adj, adj + E, etype, ntype,
                                              moffs, tcur, S, nidx, N, E);
    p2_sort_kernel<<<nbins, 256, 0, stream>>>(S, moffs, offs, M, N, E, NBLK1);
    proj_kernel<<<dim3(128, 3, TT), 64, 0, stream>>>(h, Wk, Wq, Wv, toff, nidx, kh16, qn, vn);
    v2q2_kernel<<<dim3(QXB, RR), 256, 0, stream>>>(vn, qn, Amsg, Aatt, pri, V2, Q2, N);
    score_kernel<<<SCORE_BLOCKS, 256, 0, stream>>>(M, kh16, Q2, rec, E);
    agg_out_kernel<<<dim3(AGG_XB, TT), 256, 0, stream>>>(offs, rec, V2, Wa, skp, toff, nidx, out);
}

// Round 8
// 230.228 us; speedup vs baseline: 1.1412x; 1.0516x over previous
//
#include <hip/hip_runtime.h>
#include <math.h>

typedef float f32x4 __attribute__((ext_vector_type(4)));
typedef short bf16x8 __attribute__((ext_vector_type(8)));
typedef _Float16 f16x8 __attribute__((ext_vector_type(8)));
typedef _Float16 f16x4 __attribute__((ext_vector_type(4)));

#define D 64
#define TT 8
#define RR 8

#define SCAN_TPB 256
#define SCAN_CH 4
#define SCAN_ELEMS (SCAN_TPB * SCAN_CH)   // 1024 elements per block

#define MAXBINS 256      // dst-bin = 256 nodes; supports N <= 65536
#define NBLK1 784        // p1 grid; must be identical in p1_hist and p1_scat (matrix indexed by block)
#define QXB 128          // v2q2 x-blocks per relation
#define SCORE_BLOCKS 2048
#define AGG_XB 256       // agg_out x-blocks per type

// ---------------- scalar helpers ----------------
__device__ __forceinline__ float bf2f(unsigned short u) {
    union { unsigned int i; float f; } x;
    x.i = ((unsigned int)u) << 16;
    return x.f;
}
__device__ __forceinline__ unsigned short f2bf(float f) {
    union { float f; unsigned int i; } x;
    x.f = f;
    unsigned int i = x.i;
    unsigned int r = (i + 0x7FFFu + ((i >> 16) & 1u)) >> 16;   // RNE
    return (unsigned short)r;
}
struct BfPair { short hi; short lo; };
__device__ __forceinline__ BfPair split2(float x) {
    BfPair p;
    unsigned short h = f2bf(x);
    p.hi = (short)h;
    p.lo = (short)f2bf(x - bf2f(h));
    return p;
}
__device__ __forceinline__ void load_A_split(const float* __restrict__ p, bf16x8& ah, bf16x8& al) {
#pragma unroll
    for (int i = 0; i < 8; ++i) {
        BfPair s = split2(p[i]);
        ah[i] = s.hi; al[i] = s.lo;
    }
}
// bf16 split B fragment, canonical cols (agg_out: col = c*16+n)
__device__ __forceinline__ void load_B_split(const float* __restrict__ W, int ks, int c, int lane,
                                             bf16x8& bh, bf16x8& bl) {
    int n = lane & 15, q = lane >> 4;
#pragma unroll
    for (int i = 0; i < 8; ++i) {
        BfPair s = split2(W[(ks * 32 + q * 8 + i) * 64 + c * 16 + n]);
        bh[i] = s.hi; bl[i] = s.lo;
    }
}
// bf16 split B fragment, PERMUTED cols (proj: col = n*4+c; store address carries the
// permutation so kh16/qn/vn memory layout stays natural feature order)
__device__ __forceinline__ void load_B_splitp(const float* __restrict__ W, int ks, int c, int lane,
                                              bf16x8& bh, bf16x8& bl) {
    int n = lane & 15, q = lane >> 4;
#pragma unroll
    for (int i = 0; i < 8; ++i) {
        BfPair s = split2(W[(ks * 32 + q * 8 + i) * 64 + n * 4 + c]);
        bh[i] = s.hi; bl[i] = s.lo;
    }
}

#define MFMA16(a, b, c) __builtin_amdgcn_mfma_f32_16x16x32_bf16(a, b, c, 0, 0, 0)
#define MFMAH(a, b, c)  __builtin_amdgcn_mfma_f32_16x16x32_f16(a, b, c, 0, 0, 0)

// 24 bf16 MFMAs: acc += (Ah+Al)@(Bh+Bl) dropping lo*lo
#define SPLIT_MFMA_BODY(acc, A0h, A0l, A1h, A1l, Bh, Bl)          \
    _Pragma("unroll")                                             \
    for (int c = 0; c < 4; ++c) {                                 \
        acc[c] = MFMA16(A0h, Bh[0][c], acc[c]);                   \
        acc[c] = MFMA16(A0l, Bh[0][c], acc[c]);                   \
        acc[c] = MFMA16(A0h, Bl[0][c], acc[c]);                   \
        acc[c] = MFMA16(A1h, Bh[1][c], acc[c]);                   \
        acc[c] = MFMA16(A1l, Bh[1][c], acc[c]);                   \
        acc[c] = MFMA16(A1h, Bl[1][c], acc[c]);                   \
    }

// ---------------- atomic-free CSR build (two-level counting sort by dst) ----------------
// p1_hist: per-block LDS histogram over dst>>8 bins -> matrix mat[bin][blk]. No global
// per-edge atomics. Also type-histogram.
__global__ void p1_hist_kernel(const int* __restrict__ dst, const int* __restrict__ nt,
                               int* __restrict__ mat, int* __restrict__ tcnt,
                               int N, int E, int nbins) {
    __shared__ int c[MAXBINS];
    __shared__ int lt[TT];
    if (threadIdx.x < MAXBINS) c[threadIdx.x] = 0;
    if (threadIdx.x < TT) lt[threadIdx.x] = 0;
    __syncthreads();
    const int stride = gridDim.x * blockDim.x;
    for (int e = blockIdx.x * blockDim.x + threadIdx.x; e < E; e += stride)
        atomicAdd(&c[dst[e] >> 8], 1);
    for (int n = blockIdx.x * blockDim.x + threadIdx.x; n < N; n += stride)
        atomicAdd(&lt[nt[n]], 1);
    __syncthreads();
    if (threadIdx.x < nbins) mat[threadIdx.x * gridDim.x + blockIdx.x] = c[threadIdx.x];
    if (threadIdx.x < TT && lt[threadIdx.x]) atomicAdd(&tcnt[threadIdx.x], lt[threadIdx.x]);
}

// ---- 2-phase device-wide exclusive scan (generic length) ----
__global__ void scan_sum_kernel(const int* __restrict__ deg, int* __restrict__ bsum, int N) {
    __shared__ int ws[SCAN_TPB / 64];
    int tid = threadIdx.x;
    int base = blockIdx.x * SCAN_ELEMS + tid * SCAN_CH;
    int s = 0;
#pragma unroll
    for (int i = 0; i < SCAN_CH; ++i) {
        int idx = base + i;
        if (idx < N) s += deg[idx];
    }
#pragma unroll
    for (int d = 32; d; d >>= 1) s += __shfl_xor(s, d, 64);
    if ((tid & 63) == 0) ws[tid >> 6] = s;
    __syncthreads();
    if (tid == 0) {
        int t = 0;
#pragma unroll
        for (int i = 0; i < SCAN_TPB / 64; ++i) t += ws[i];
        bsum[blockIdx.x] = t;
    }
}
__global__ void scan_out_kernel(const int* __restrict__ deg, const int* __restrict__ bsum, int nsb,
                                int* __restrict__ off, int N, int Etot,
                                const int* __restrict__ tcnt, int* __restrict__ toff, int* __restrict__ tcur) {
    __shared__ int ts[SCAN_TPB];
    __shared__ int bb;
    int tid = threadIdx.x;
    if (tid < 64) {
        int v = 0;
        if (nsb <= 64) {
            v = (tid < nsb && tid < blockIdx.x) ? bsum[tid] : 0;
#pragma unroll
            for (int d = 32; d; d >>= 1) v += __shfl_xor(v, d, 64);
        } else if (tid == 0) {
            for (int b = 0; b < blockIdx.x; ++b) v += bsum[b];
        }
        if (tid == 0) bb = v;
    }
    if (blockIdx.x == 0 && tid == 1) {
        int a = 0;
        for (int t = 0; t < TT; ++t) { toff[t] = a; tcur[t] = a; a += tcnt[t]; }
        toff[TT] = a;
        off[N] = Etot;
    }
    int base = blockIdx.x * SCAN_ELEMS + tid * SCAN_CH;
    int loc[SCAN_CH];
    int s = 0;
#pragma unroll
    for (int i = 0; i < SCAN_CH; ++i) {
        int idx = base + i;
        int v = (idx < N) ? deg[idx] : 0;
        loc[i] = v; s += v;
    }
    ts[tid] = s;
    __syncthreads();
    for (int sh = 1; sh < SCAN_TPB; sh <<= 1) {
        int v = (tid >= sh) ? ts[tid - sh] : 0;
        __syncthreads();
        ts[tid] += v;
        __syncthreads();
    }
    int run = bb + ((tid > 0) ? ts[tid - 1] : 0);
#pragma unroll
    for (int i = 0; i < SCAN_CH; ++i) {
        int idx = base + i;
        if (idx < N) { off[idx] = run; run += loc[i]; }
    }
}

// p1_scat: scatter edges to their bin chunk (base from scanned matrix + fresh LDS ranks;
// same edge->block mapping as p1_hist so counts match). Also builds type-grouped nidx
// (single-shot: NBLK1*256 >= N).
__global__ void p1_scat_kernel(const int* __restrict__ src, const int* __restrict__ dst,
                               const int* __restrict__ et, const int* __restrict__ nt,
                               const int* __restrict__ moffs, int* __restrict__ tcur,
                               int2* __restrict__ S, int* __restrict__ nidx, int N, int E) {
    __shared__ int c[MAXBINS];
    __shared__ int lt[TT], bt[TT];
    if (threadIdx.x < MAXBINS) c[threadIdx.x] = 0;
    if (threadIdx.x < TT) lt[threadIdx.x] = 0;
    __syncthreads();
    const int n = blockIdx.x * blockDim.x + threadIdx.x;
    int t = 0, trank = 0;
    if (n < N) { t = nt[n]; trank = atomicAdd(&lt[t], 1); }
    const int stride = gridDim.x * blockDim.x;
    for (int e = blockIdx.x * blockDim.x + threadIdx.x; e < E; e += stride) {
        int d = dst[e];
        int b = d >> 8;
        int rk = atomicAdd(&c[b], 1);
        int pos = moffs[b * gridDim.x + blockIdx.x] + rk;
        int2 s2; s2.x = src[e]; s2.y = (d << 3) | et[e];
        S[pos] = s2;
    }
    __syncthreads();
    if (threadIdx.x < TT)
        bt[threadIdx.x] = lt[threadIdx.x] ? atomicAdd(&tcur[threadIdx.x], lt[threadIdx.x]) : 0;
    __syncthreads();
    if (n < N) nidx[bt[t] + trank] = n;
}

// p2: one block per 256-dst bin; LDS counting sort by dst -> final dst-CSR meta M + offs.
// Within-dst order is arbitrary (matches original erank semantics).
__global__ void p2_sort_kernel(const int2* __restrict__ S, const int* __restrict__ moffs,
                               int* __restrict__ offs, int2* __restrict__ M,
                               int N, int E, int nblk1) {
    const int b = blockIdx.x, tid = threadIdx.x;
    const int A1 = moffs[b * nblk1];
    const int A2 = moffs[(b + 1) * nblk1];
    __shared__ int dc[MAXBINS], ds[MAXBINS], dr[MAXBINS];
    dc[tid] = 0; dr[tid] = 0;
    __syncthreads();
    for (int e = A1 + tid; e < A2; e += blockDim.x)
        atomicAdd(&dc[(S[e].y >> 3) & 255], 1);
    __syncthreads();
    int v = dc[tid];
    ds[tid] = v;
    __syncthreads();
    for (int sh = 1; sh < MAXBINS; sh <<= 1) {
        int u = (tid >= sh) ? ds[tid - sh] : 0;
        __syncthreads();
        ds[tid] += u;
        __syncthreads();
    }
    int excl = tid ? ds[tid - 1] : 0;
    int node = b * 256 + tid;
    if (node < N) offs[node] = A1 + excl;
    dc[tid] = excl;                        // counts no longer needed; keep excl in LDS
    __syncthreads();
    for (int e = A1 + tid; e < A2; e += blockDim.x) {
        int2 s2 = S[e];
        int dl = (s2.y >> 3) & 255;
        int rk = atomicAdd(&dr[dl], 1);
        M[A1 + dc[dl] + rk] = s2;
    }
    if (b == 0 && tid == 0) offs[N] = E;
}

// ---------------- node projections (unchanged) ----------------
__global__ void proj_kernel(const float* __restrict__ h,
                            const float* __restrict__ Wk, const float* __restrict__ Wq,
                            const float* __restrict__ Wv,
                            const int* __restrict__ toff, const int* __restrict__ nidx,
                            _Float16* __restrict__ kh16,
                            _Float16* __restrict__ qout, _Float16* __restrict__ vout) {
    const int t = blockIdx.z, a = blockIdx.y, lane = threadIdx.x;
    const int beg = toff[t], end = toff[t + 1], cnt = end - beg;
    if (cnt <= 0) return;
    const int nstrips = (cnt + 15) >> 4;
    const float* W = (a == 0 ? Wk : (a == 1 ? Wq : Wv)) + (size_t)t * 4096;
    const int m = lane & 15, quad = lane >> 4;

    bf16x8 Bh[2][4], Bl[2][4];
#pragma unroll
    for (int ks = 0; ks < 2; ++ks)
#pragma unroll
        for (int c = 0; c < 4; ++c) load_B_splitp(W, ks, c, lane, Bh[ks][c], Bl[ks][c]);

    _Float16* out = (a == 0) ? kh16 : (a == 1 ? qout : vout);

    for (int s = blockIdx.x; s < nstrips; s += gridDim.x) {
        int base = beg + s * 16;
        int rA = base + m; if (rA > end - 1) rA = end - 1;
        const float* hp = h + (size_t)nidx[rA] * D;
        bf16x8 A0h, A0l, A1h, A1l;
        load_A_split(hp + quad * 8, A0h, A0l);
        load_A_split(hp + 32 + quad * 8, A1h, A1l);
        f32x4 acc[4];
#pragma unroll
        for (int c = 0; c < 4; ++c) acc[c] = (f32x4){0.f, 0.f, 0.f, 0.f};
        SPLIT_MFMA_BODY(acc, A0h, A0l, A1h, A1l, Bh, Bl)
#pragma unroll
        for (int reg = 0; reg < 4; ++reg) {
            int rr = base + quad * 4 + reg;
            if (rr < end) {
                int nid = nidx[rr];
                f16x4 o;
#pragma unroll
                for (int c = 0; c < 4; ++c) o[c] = (_Float16)acc[c][reg];
                *(f16x4*)(out + (size_t)nid * D + m * 4) = o;
            }
        }
    }
}

// ---------------- V2 + Q2 build (unchanged) ----------------
// V2[s*8+r] = vn[s] @ Amsg_r          (f16)
// Q2[d*8+r] = (Aatt_r @ qn[d]) * pri_r/8   (A^T fragment, scale folded; row id == (d<<3)|r)
__global__ void v2q2_kernel(const _Float16* __restrict__ vn, const _Float16* __restrict__ qn,
                            const float* __restrict__ Amsg, const float* __restrict__ Aatt,
                            const float* __restrict__ pri,
                            _Float16* __restrict__ V2, _Float16* __restrict__ Q2, int N) {
    const int r = blockIdx.y;
    const int lane = threadIdx.x & 63;
    const int wv = threadIdx.x >> 6;
    const int m = lane & 15, quad = lane >> 4;
    const int g = blockIdx.x * 4 + wv;
    const int nstrips = (N + 15) >> 4;
    const float scale = pri[r] * 0.125f;
    const float* Wv = Amsg + (size_t)r * 4096;
    const float* Wq = Aatt + (size_t)r * 4096;

    f16x8 Bv[2][4], Bq[2][4];
    {
        const int n = lane & 15, q = lane >> 4;
#pragma unroll
        for (int ks = 0; ks < 2; ++ks)
#pragma unroll
            for (int c = 0; c < 4; ++c) {
                f16x8 bv, bq;
#pragma unroll
                for (int i = 0; i < 8; ++i) {
                    int kk = ks * 32 + q * 8 + i;
                    int col = n * 4 + c;                       // permuted col (matches f16x4 store addr)
                    bv[i] = (_Float16)Wv[kk * 64 + col];
                    bq[i] = (_Float16)(Wq[col * 64 + kk] * scale);   // A^T, scale folded
                }
                Bv[ks][c] = bv; Bq[ks][c] = bq;
            }
    }

    for (int s = g; s < nstrips; s += QXB * 4) {
        int base = s * 16;
        int rA = base + m; if (rA > N - 1) rA = N - 1;
        // V2 from vn
        {
            f16x8 A0 = *(const f16x8*)(vn + (size_t)rA * D + quad * 8);
            f16x8 A1 = *(const f16x8*)(vn + (size_t)rA * D + 32 + quad * 8);
            f32x4 acc[4];
#pragma unroll
            for (int c = 0; c < 4; ++c) acc[c] = (f32x4){0.f, 0.f, 0.f, 0.f};
#pragma unroll
            for (int c = 0; c < 4; ++c) {
                acc[c] = MFMAH(A0, Bv[0][c], acc[c]);
                acc[c] = MFMAH(A1, Bv[1][c], acc[c]);
            }
#pragma unroll
            for (int reg = 0; reg < 4; ++reg) {
                int rr = base + quad * 4 + reg;
                if (rr < N) {
                    f16x4 o;
#pragma unroll
                    for (int c = 0; c < 4; ++c) o[c] = (_Float16)acc[c][reg];
                    *(f16x4*)(V2 + ((size_t)rr * RR + r) * D + m * 4) = o;
                }
            }
        }
        // Q2 from qn
        {
            f16x8 A0 = *(const f16x8*)(qn + (size_t)rA * D + quad * 8);
            f16x8 A1 = *(const f16x8*)(qn + (size_t)rA * D + 32 + quad * 8);
            f32x4 acc[4];
#pragma unroll
            for (int c = 0; c < 4; ++c) acc[c] = (f32x4){0.f, 0.f, 0.f, 0.f};
#pragma unroll
            for (int c = 0; c < 4; ++c) {
                acc[c] = MFMAH(A0, Bq[0][c], acc[c]);
                acc[c] = MFMAH(A1, Bq[1][c], acc[c]);
            }
#pragma unroll
            for (int reg = 0; reg < 4; ++reg) {
                int rr = base + quad * 4 + reg;
                if (rr < N) {
                    f16x4 o;
#pragma unroll
                    for (int c = 0; c < 4; ++c) o[c] = (_Float16)acc[c][reg];
                    *(f16x4*)(Q2 + ((size_t)rr * RR + r) * D + m * 4) = o;
                }
            }
        }
    }
}

// ---------------- per-edge scores (cooperative: 4 lanes per edge) ----------------
// Old: 1 edge/lane, 16 serial 8B loads -> each wave instr touches 64 lines.
// New: lane = edge-slot*4 + chunk; each lane loads one contiguous 32B chunk of the
// k-row and Q2-row (4 lanes cover a 128B row -> ~16 lines/instr), 2-round shfl_xor
// quad reduce. Meta loaded once coalesced (lanes 0-15) and shfl-broadcast.
__global__ void score_kernel(const int2* __restrict__ M, const _Float16* __restrict__ kh16,
                             const _Float16* __restrict__ Q2, int2* __restrict__ rec, int E) {
    const int lane = threadIdx.x & 63;
    const int sub = lane >> 2;         // edge slot 0..15
    const int ch  = lane & 3;          // 16-f16 chunk 0..3
    const int gwave = (blockIdx.x * blockDim.x + threadIdx.x) >> 6;
    const int nwaves = (gridDim.x * blockDim.x) >> 6;

    for (int base = gwave * 16; base < E; base += nwaves * 16) {
        // lanes 0..15 load meta coalesced; broadcast to the edge's 4 lanes
        int2 md0; md0.x = 0; md0.y = 0;
        int e16 = base + lane;
        if (lane < 16 && e16 < E) md0 = M[e16];
        int msrc = __shfl(md0.x, sub, 64);
        int mkey = __shfl(md0.y, sub, 64);
        const int e = base + sub;

        const _Float16* kr = kh16 + (size_t)msrc * D + ch * 16;
        const _Float16* qr = Q2 + (size_t)mkey * D + ch * 16;
        f16x8 k0 = *(const f16x8*)kr;
        f16x8 k1 = *(const f16x8*)(kr + 8);
        f16x8 q0 = *(const f16x8*)qr;
        f16x8 q1 = *(const f16x8*)(qr + 8);
        float acc = 0.f;
#pragma unroll
        for (int u = 0; u < 8; ++u) acc += (float)k0[u] * (float)q0[u];
#pragma unroll
        for (int u = 0; u < 8; ++u) acc += (float)k1[u] * (float)q1[u];
        acc += __shfl_xor(acc, 1, 64);
        acc += __shfl_xor(acc, 2, 64);

        if (ch == 0 && e < E) {
            int2 rc;
            rc.x = __float_as_int(acc);                // scale folded into Q2
            rc.y = (msrc << 3) | (mkey & 7);           // V2 row id
            rec[e] = rc;
        }
    }
}

// ---------------- fused per-dst softmax+aggregation + output transform (unchanged) ----------------
__global__ void agg_out_kernel(const int* __restrict__ offs, const int2* __restrict__ rec,
                               const _Float16* __restrict__ V2,
                               const float* __restrict__ Wa, const float* __restrict__ skp,
                               const int* __restrict__ toff, const int* __restrict__ nidx,
                               float* __restrict__ out) {
    const int t = blockIdx.y;
    const int beg = toff[t], end = toff[t + 1], cnt = end - beg;
    if (cnt <= 0) return;
    const int nstrips = (cnt + 15) >> 4;
    const int lane = threadIdx.x & 63;
    const int wv = threadIdx.x >> 6;          // 4 waves
    const int quad = lane >> 4, ql = lane & 15;
    const int q16 = wv * 4 + quad;            // node slot 0..15
    const int qb = quad << 4;
    const int m = lane & 15, qd = lane >> 4;  // MFMA roles
    const float sg = 1.f / (1.f + __expf(-skp[t]));

    __shared__ float As[16][68];              // padded stride breaks LDS bank conflicts

    bf16x8 Bh2[2], Bl2[2];
    const float* W = Wa + (size_t)t * 4096;
#pragma unroll
    for (int ks = 0; ks < 2; ++ks) load_B_split(W, ks, wv, lane, Bh2[ks], Bl2[ks]);

    for (int s = blockIdx.x; s < nstrips; s += gridDim.x) {
        int base = beg + s * 16;
        int rr = base + q16; if (rr > end - 1) rr = end - 1;   // tail: duplicate last node
        int i = nidx[rr];
        const int ebeg = offs[i], eend = offs[i + 1];
        float mmax = -INFINITY, lsum = 0.f;
        float a0 = 0.f, a1 = 0.f, a2 = 0.f, a3 = 0.f;
        for (int cs = ebeg; cs < eend; cs += 16) {
            int cl = eend - cs; if (cl > 16) cl = 16;
            int2 rc; rc.y = 0;
            float sc = -INFINITY;
            if (ql < cl) { rc = rec[cs + ql]; sc = __int_as_float(rc.x); }
            float cm = sc;
#pragma unroll
            for (int d = 8; d; d >>= 1) cm = fmaxf(cm, __shfl_xor(cm, d, 64));
            float mn = fmaxf(mmax, cm);
            float cf = __expf(mmax - mn);
            float ex = (ql < cl) ? __expf(sc - mn) : 0.f;
            float csum = ex;
#pragma unroll
            for (int d = 8; d; d >>= 1) csum += __shfl_xor(csum, d, 64);
            lsum = lsum * cf + csum;
            a0 *= cf; a1 *= cf; a2 *= cf; a3 *= cf;
            for (int e = 0; e < cl; e += 4) {
                float w0 = __shfl(ex, qb + e, 64),     w1 = __shfl(ex, qb + e + 1, 64);
                float w2 = __shfl(ex, qb + e + 2, 64), w3 = __shfl(ex, qb + e + 3, 64);
                int   i0 = __shfl(rc.y, qb + e, 64),     i1 = __shfl(rc.y, qb + e + 1, 64);
                int   i2 = __shfl(rc.y, qb + e + 2, 64), i3 = __shfl(rc.y, qb + e + 3, 64);
                f16x4 v0 = *(const f16x4*)(V2 + (size_t)i0 * D + ql * 4);
                f16x4 v1 = *(const f16x4*)(V2 + (size_t)i1 * D + ql * 4);
                f16x4 v2 = *(const f16x4*)(V2 + (size_t)i2 * D + ql * 4);
                f16x4 v3 = *(const f16x4*)(V2 + (size_t)i3 * D + ql * 4);
                a0 += w0 * (float)v0[0] + w1 * (float)v1[0] + w2 * (float)v2[0] + w3 * (float)v3[0];
                a1 += w0 * (float)v0[1] + w1 * (float)v1[1] + w2 * (float)v2[1] + w3 * (float)v3[1];
                a2 += w0 * (float)v0[2] + w1 * (float)v1[2] + w2 * (float)v2[2] + w3 * (float)v3[2];
                a3 += w0 * (float)v0[3] + w1 * (float)v1[3] + w2 * (float)v2[3] + w3 * (float)v3[3];
            }
            mmax = mn;
        }
        float inv = 1.f / (lsum + 1e-16f);
        As[q16][ql * 4 + 0] = a0 * inv;
        As[q16][ql * 4 + 1] = a1 * inv;
        As[q16][ql * 4 + 2] = a2 * inv;
        As[q16][ql * 4 + 3] = a3 * inv;
        __syncthreads();

        bf16x8 A0h, A0l, A1h, A1l;
        load_A_split(&As[m][qd * 8], A0h, A0l);
        load_A_split(&As[m][32 + qd * 8], A1h, A1l);
        f32x4 acc = (f32x4){0.f, 0.f, 0.f, 0.f};
        acc = MFMA16(A0h, Bh2[0], acc);
        acc = MFMA16(A0l, Bh2[0], acc);
        acc = MFMA16(A0h, Bl2[0], acc);
        acc = MFMA16(A1h, Bh2[1], acc);
        acc = MFMA16(A1l, Bh2[1], acc);
        acc = MFMA16(A1h, Bl2[1], acc);
#pragma unroll
        for (int reg = 0; reg < 4; ++reg) {
            int rrr = base + qd * 4 + reg;
            if (rrr < end)
                out[(size_t)nidx[rrr] * D + wv * 16 + m] = acc[reg] * sg;
        }
        __syncthreads();   // protect As before next strip
    }
}

// ---------------- launch ----------------
extern "C" void kernel_launch(void* const* d_in, const int* in_sizes, int n_in,
                              void* d_out, int out_size, void* d_ws, size_t ws_size,
                              hipStream_t stream) {
    const float* h     = (const float*)d_in[0];
    const int*   adj   = (const int*)d_in[1];     // [2,E]: src row then dst row
    const int*   etype = (const int*)d_in[2];
    const int*   ntype = (const int*)d_in[3];
    const float* Wk    = (const float*)d_in[6];
    const float* Wq    = (const float*)d_in[7];
    const float* Wv    = (const float*)d_in[8];
    const float* Wa    = (const float*)d_in[9];
    const float* pri   = (const float*)d_in[10];
    const float* Aatt  = (const float*)d_in[11];
    const float* Amsg  = (const float*)d_in[12];
    const float* skp   = (const float*)d_in[13];
    const int N = in_sizes[3];
    const int E = in_sizes[2];
    float* out = (float*)d_out;

    const int nbins = (N + 255) >> 8;             // 256-node dst bins (N <= 65536)
    const int Nscan = nbins * NBLK1;              // matrix length for the scan
    const int nsb = (Nscan + SCAN_ELEMS - 1) / SCAN_ELEMS;

    char* w = (char*)d_ws;
    auto alloc = [&](size_t b) { char* p = w; w += (b + 255) & ~(size_t)255; return p; };
    _Float16* kh16 = (_Float16*)alloc((size_t)N * D * 2);
    _Float16* qn   = (_Float16*)alloc((size_t)N * D * 2);
    _Float16* vn   = (_Float16*)alloc((size_t)N * D * 2);
    _Float16* V2   = (_Float16*)alloc((size_t)N * RR * D * 2);
    _Float16* Q2   = (_Float16*)alloc((size_t)N * RR * D * 2);
    int2* S   = (int2*)alloc((size_t)E * 8);      // bin-sorted meta; DEAD after p2 -> rec aliases it
    int2* M   = (int2*)alloc((size_t)E * 8);      // dst-sorted meta
    int2* rec = S;                                // alias: S consumed by p2 before score writes rec
    int* mat   = (int*)alloc((size_t)Nscan * 4);
    int* moffs = (int*)alloc((size_t)(Nscan + 1) * 4);
    int* bsum  = (int*)alloc((size_t)nsb * 4);
    int* offs  = (int*)alloc((size_t)(N + 1) * 4);
    int* nidx  = (int*)alloc((size_t)N * 4);
    int* tcnt  = (int*)alloc(64);
    int* tcur  = (int*)alloc(64);
    int* toff  = (int*)alloc(64);

    (void)hipMemsetAsync(tcnt, 0, 32, stream);

    p1_hist_kernel<<<NBLK1, 256, 0, stream>>>(adj + E, ntype, mat, tcnt, N, E, nbins);
    scan_sum_kernel<<<nsb, SCAN_TPB, 0, stream>>>(mat, bsum, Nscan);
    scan_out_kernel<<<nsb, SCAN_TPB, 0, stream>>>(mat, bsum, nsb, moffs, Nscan, E,
                                                  tcnt, toff, tcur);
    p1_scat_kernel<<<NBLK1, 256, 0, stream>>>(adj, adj + E, etype, ntype,
                                              moffs, tcur, S, nidx, N, E);
    p2_sort_kernel<<<nbins, 256, 0, stream>>>(S, moffs, offs, M, N, E, NBLK1);
    proj_kernel<<<dim3(128, 3, TT), 64, 0, stream>>>(h, Wk, Wq, Wv, toff, nidx, kh16, qn, vn);
    v2q2_kernel<<<dim3(QXB, RR), 256, 0, stream>>>(vn, qn, Amsg, Aatt, pri, V2, Q2, N);
    score_kernel<<<SCORE_BLOCKS, 256, 0, stream>>>(M, kh16, Q2, rec, E);
    agg_out_kernel<<<dim3(AGG_XB, TT), 256, 0, stream>>>(offs, rec, V2, Wa, skp, toff, nidx, out);
}